// Round 12
// baseline (409.157 us; speedup 1.0000x reference)
//
#include <hip/hip_runtime.h>

typedef float f32x4 __attribute__((ext_vector_type(4)));
typedef __bf16 bf16x8 __attribute__((ext_vector_type(8)));

typedef __attribute__((address_space(3))) unsigned char lds_u8;
typedef __attribute__((address_space(1))) const unsigned char g_u8c;

__device__ __forceinline__ unsigned short f2bf(float f) {
  unsigned int u = __float_as_uint(f);
  u += 0x7FFFu + ((u >> 16) & 1u);   // round-to-nearest-even
  return (unsigned short)(u >> 16);
}
__device__ __forceinline__ bf16x8 cvt8(float4 x, float4 y) {
  bf16x8 r;
  r[0] = (__bf16)x.x; r[1] = (__bf16)x.y; r[2] = (__bf16)x.z; r[3] = (__bf16)x.w;
  r[4] = (__bf16)y.x; r[5] = (__bf16)y.y; r[6] = (__bf16)y.z; r[7] = (__bf16)y.w;
  return r;
}
__device__ __forceinline__ void gload16(const void* g, void* l) {
  __builtin_amdgcn_global_load_lds((g_u8c*)g, (lds_u8*)l, 16, 0, 0);
}
__device__ __forceinline__ void poll_ge(volatile int* p, int target) {
  while (*p < target) __builtin_amdgcn_s_sleep(1);
  asm volatile("" ::: "memory");             // compiler fence: no hoisting past poll
}

// ---- k_prep: weights -> bf16, fragment-contiguous (validated r7-r11) ----
// b-frag for (kt,ctg): wt[(kt*8+ctg)*512 + lane*8 + j]; kt 0..3 = W_self,
// kt 4..7 = W_neigh; lane=lg*16+l15 -> (n=ctg*16+l15, k=kt*32+lg*8+j).
__global__ void k_prep(const float* __restrict__ Ws, const float* __restrict__ Wn,
                       const float* __restrict__ bs, const float* __restrict__ bn,
                       unsigned short* __restrict__ wt, float* __restrict__ bias) {
  int idx = blockIdx.x * 256 + threadIdx.x;   // 0..32767
  int n = idx >> 8, k = idx & 255;
  float v = (k < 128) ? Ws[k * 128 + n] : Wn[(k - 128) * 128 + n];
  int ct = n >> 4, l15 = n & 15, kt = k >> 5, lg = (k >> 3) & 3, j = k & 7;
  wt[(((kt << 3) | ct) << 9) + (((lg << 4) | l15) << 3) + j] = f2bf(v);
  if (idx < 128) bias[idx] = bs[idx] + bn[idx];
}

#define SPAN 256   // 8 tiles x 32 rows per WG

// ---- Fused producer/consumer: 4 producer waves stream src+dstf into a
// 2-slot LDS ring (~100% issue duty); 4 consumer waves (persistent B, 32
// cols each) run MFMA O/Y + Z=M@Y scan + store. LDS-flag sync, no barriers
// in the loop. A-tile swizzle <<4 = conflict-free b128 reads. ----
__global__ __launch_bounds__(512, 4) void k_fused(
    const float* __restrict__ src, const float* __restrict__ dstf,
    const int* __restrict__ dst, const unsigned short* __restrict__ wt,
    const float* __restrict__ bias, float* __restrict__ out, int E, int nwg)
{
  __shared__ __align__(16) unsigned char sbuf[2][16384];   // src f32 32x512, swz<<4
  __shared__ __align__(16) unsigned char dbuf[2][16384];   // dstf f32 32x512, swz<<4
  __shared__ __align__(16) unsigned char ylds[4][2560];    // per-consumer Y bounce
  __shared__ int ready[2];                                 // producer -> consumer
  __shared__ int done[2];                                  // consumer -> producer

  const int tid = threadIdx.x;
  const int lane = tid & 63, wid = tid >> 6;
  const int l15 = lane & 15, lg = lane >> 4, l31 = lane & 31;
  const long emax = (long)E - 1;

  // bijective XCD swizzle (m204)
  const int bid = blockIdx.x;
  const int q = nwg >> 3, r = nwg & 7;
  const int xcd = bid & 7, ix = bid >> 3;
  const int swb = (xcd < r ? xcd * (q + 1) : r * (q + 1) + (xcd - r) * q) + ix;

  const long W0 = (long)swb * SPAN;
  if (W0 >= E) return;                          // WG-uniform
  const long Wend = (W0 + SPAN < (long)E) ? W0 + SPAN : (long)E;
  const int nt = (int)((Wend - W0 + 31) >> 5);

  if (tid == 0) { ready[0] = 0; ready[1] = 0; done[0] = 0; done[1] = 0; }
  __syncthreads();                              // flags visible to all 8 waves

  // ================= PRODUCERS (wid 4..7) =================
  if (wid >= 4) {
    const int pid = wid - 4;
    for (int t = 0; t < nt; ++t) {
      const int slot = t & 1;
      if (t >= 2) poll_ge((volatile int*)&done[slot], 4 * (t >> 1));
      const long tb = W0 + (long)t * 32;
      #pragma unroll
      for (int i2 = 0; i2 < 4; ++i2) {          // pid stages rows [pid*8, pid*8+8)
        int i = pid * 4 + i2;
        int r2 = i * 2 + (lane >> 5);
        long gr = tb + r2; if (gr > emax) gr = emax;
        int colb = (l31 << 4) ^ ((r2 & 7) << 4);   // inverse swizzle on source
        gload16((const char*)src + gr * 512 + colb, sbuf[slot] + i * 1024);
        gload16((const char*)dstf + gr * 512 + colb, dbuf[slot] + i * 1024);
      }
      asm volatile("s_waitcnt vmcnt(0)" ::: "memory");   // quarter landed in LDS
      if (lane == 0) atomicAdd(&ready[slot], 1);
    }
    return;
  }

  // ================= CONSUMERS (wid 0..3) =================
  unsigned char* yw = ylds[wid];
  float bc[2] = { bias[wid * 32 + l15], bias[wid * 32 + 16 + l15] };

  // persistent B: cols [wid*32, wid*32+32), 16 frags = 64 VGPRs
  bf16x8 B[8][2];
  #pragma unroll
  for (int kt = 0; kt < 8; ++kt)
    #pragma unroll
    for (int ctt = 0; ctt < 2; ++ctt)
      B[kt][ctt] = *(const bf16x8*)(wt + (((kt << 3) | (wid * 2 + ctt)) << 9) + (lane << 3));

  // prologue: bucket start before W0 -> pos0, carry[2] (output space)
  int d0 = dst[W0];
  long back = W0 - 1 - lane;
  long backc = back < 0 ? 0 : back;
  int bd = dst[backc];
  unsigned long long mm = __ballot((back >= 0) && (bd == d0));
  unsigned long long nmm = ~mm;
  int L = (nmm == 0ull) ? 64 : __builtin_ctzll(nmm);
  long s = W0 - L;
  while (s > 0 && dst[s - 1] == d0) --s;        // bucket >64 deep: ~never
  int pos0 = (int)(W0 - s);

  float carry[2] = {0.f, 0.f};
  if (pos0 > 0) {
    float* cw = (float*)yw;                     // reuse Y-bounce space in prologue
    float px = 0.f, py = 0.f;
    for (long e = s; e < W0; ) {
      int nb = (int)(W0 - e); if (nb > 8) nb = 8;
      float2 tv[8];
      #pragma unroll
      for (int j = 0; j < 8; ++j)
        if (j < nb) tv[j] = *(const float2*)(src + (e + j) * 128 + lane * 2);
      #pragma unroll
      for (int j = 0; j < 8; ++j)
        if (j < nb) { px += tv[j].x; py += tv[j].y; }
      e += nb;
    }
    cw[lane * 2] = px; cw[lane * 2 + 1] = py;
    asm volatile("s_waitcnt lgkmcnt(0)" ::: "memory");
    #pragma unroll
    for (int ctt = 0; ctt < 2; ++ctt) {
      f32x4 accc = {0.f, 0.f, 0.f, 0.f};        // carry = presum @ Wn (row-0 MFMA)
      #pragma unroll
      for (int kt = 0; kt < 4; ++kt) {
        float4 x = {0,0,0,0}, y = {0,0,0,0};
        if (l15 == 0) {
          x = *(const float4*)(cw + kt * 32 + lg * 8);
          y = *(const float4*)(cw + kt * 32 + lg * 8 + 4);
        }
        bf16x8 a = cvt8(x, y);
        accc = __builtin_amdgcn_mfma_f32_16x16x32_bf16(a, B[kt + 4][ctt], accc, 0, 0, 0);
      }
      carry[ctt] = __shfl(accc[0], l15);        // D row0: lanes 0..15, comp 0
    }
  }

  for (int t = 0; t < nt; ++t) {
    const int slot = t & 1;
    const long tb = W0 + (long)t * 32;
    const unsigned char* sb = sbuf[slot];
    const unsigned char* db = dbuf[slot];

    // reset mask (independent global loads; before the poll)
    long rc = tb + l31; if (rc > emax) rc = emax;
    int dcur = dst[rc];
    long rp = rc - 1; if (rp < 0) rp = 0;
    int dprev = dst[rp];
    unsigned mask = (unsigned)(__ballot((lane < 32) && (tb + l31 > 0) && (dcur != dprev)));

    poll_ge((volatile int*)&ready[slot], 4 * ((t >> 1) + 1));   // tile staged

    // ---- O = dstf@Ws, Y = src@Wn from LDS (swz<<4: conflict-free) ----
    f32x4 accO[2][2] = {{{0,0,0,0},{0,0,0,0}},{{0,0,0,0},{0,0,0,0}}};
    f32x4 accY[2][2] = {{{0,0,0,0},{0,0,0,0}},{{0,0,0,0},{0,0,0,0}}};
    #pragma unroll
    for (int rt = 0; rt < 2; ++rt) {
      int row = rt * 16 + l15;
      const int sw = (row & 7) << 4;
      #pragma unroll
      for (int kt = 0; kt < 4; ++kt) {
        int c0 = kt * 128 + lg * 32;
        float4 sx = *(const float4*)(sb + row * 512 + (c0 ^ sw));
        float4 sy = *(const float4*)(sb + row * 512 + ((c0 + 16) ^ sw));
        float4 dx = *(const float4*)(db + row * 512 + (c0 ^ sw));
        float4 dy = *(const float4*)(db + row * 512 + ((c0 + 16) ^ sw));
        bf16x8 aS = cvt8(sx, sy);
        bf16x8 aD = cvt8(dx, dy);
        #pragma unroll
        for (int ctt = 0; ctt < 2; ++ctt) {
          accO[rt][ctt] = __builtin_amdgcn_mfma_f32_16x16x32_bf16(aD, B[kt][ctt], accO[rt][ctt], 0, 0, 0);
          accY[rt][ctt] = __builtin_amdgcn_mfma_f32_16x16x32_bf16(aS, B[kt + 4][ctt], accY[rt][ctt], 0, 0, 0);
        }
      }
    }

    // ---- M fragments: M[r][e] = 1 iff start(r) <= e <= r ----
    bf16x8 Mf[2];
    #pragma unroll
    for (int rt = 0; rt < 2; ++rt) {
      int rr = rt * 16 + l15;
      unsigned bits = mask & (0xFFFFFFFFu >> (31 - rr));
      int sr = (bits == 0) ? 0 : (31 - __clz(bits));
      union { unsigned u[4]; bf16x8 v; } mu;
      #pragma unroll
      for (int p = 0; p < 4; ++p) {
        int e0 = lg * 8 + p * 2;
        unsigned lo = (e0 >= sr && e0 <= rr) ? 0x3F80u : 0u;
        unsigned hi = (e0 + 1 >= sr && e0 + 1 <= rr) ? 0x3F80u : 0u;
        mu.u[p] = lo | (hi << 16);
      }
      Mf[rt] = mu.v;
    }

    // ---- Z = M@Y per ct (wave-private LDS bounce, stride 80) ----
    f32x4 accZ[2][2];
    #pragma unroll
    for (int ctt = 0; ctt < 2; ++ctt) {
      #pragma unroll
      for (int rt = 0; rt < 2; ++rt) {
        unsigned lo = (unsigned)f2bf(accY[rt][ctt][0]) | ((unsigned)f2bf(accY[rt][ctt][1]) << 16);
        unsigned hi = (unsigned)f2bf(accY[rt][ctt][2]) | ((unsigned)f2bf(accY[rt][ctt][3]) << 16);
        *(unsigned long long*)(yw + ctt * 1280 + l15 * 80 + rt * 32 + lg * 8) =
            (unsigned long long)lo | ((unsigned long long)hi << 32);
      }
      asm volatile("s_waitcnt lgkmcnt(0)" ::: "memory");
      bf16x8 yb = *(const bf16x8*)(yw + ctt * 1280 + l15 * 80 + lg * 16);
      #pragma unroll
      for (int rt = 0; rt < 2; ++rt) {
        f32x4 z = {0.f, 0.f, 0.f, 0.f};
        accZ[rt][ctt] = __builtin_amdgcn_mfma_f32_16x16x32_bf16(Mf[rt], yb, z, 0, 0, 0);
      }
    }

    // raw Z[31] for carry update (row 31 -> lane 48+l15, comp 3)
    float z31[2];
    #pragma unroll
    for (int ctt = 0; ctt < 2; ++ctt) z31[ctt] = __shfl(accZ[1][ctt][3], 48 + l15);

    // ---- epilogue: scale by 1/count, +carry on head rows, +O+bias, store ----
    #pragma unroll
    for (int rt = 0; rt < 2; ++rt) {
      #pragma unroll
      for (int i = 0; i < 4; ++i) {
        int rr = rt * 16 + lg * 4 + i;
        unsigned bits = mask & (0xFFFFFFFFu >> (31 - rr));
        float cnt, u;
        if (bits == 0) { cnt = (float)(rr + 1 + pos0); u = 1.f; }
        else { cnt = (float)(rr - (31 - __clz(bits)) + 1); u = 0.f; }
        float inv = __builtin_amdgcn_rcpf(cnt);
        long grow = tb + rr;
        if (grow < E) {
          float* op = out + grow * 128 + wid * 32 + l15;
          op[0]  = accO[rt][0][i] + bc[0] + (accZ[rt][0][i] + u * carry[0]) * inv;
          op[16] = accO[rt][1][i] + bc[1] + (accZ[rt][1][i] + u * carry[1]) * inv;
        }
      }
    }

    // carry/pos0 update (wave-uniform)
    if (mask == 0) { carry[0] += z31[0]; carry[1] += z31[1]; pos0 += 32; }
    else           { carry[0]  = z31[0]; carry[1]  = z31[1]; pos0 = __clz(mask) + 1; }

    asm volatile("" ::: "memory");              // LDS reads stay before done++
    if (lane == 0) atomicAdd(&done[slot], 1);
  }
}

extern "C" void kernel_launch(void* const* d_in, const int* in_sizes, int n_in,
                              void* d_out, int out_size, void* d_ws, size_t ws_size,
                              hipStream_t stream) {
  const float* src_feat = (const float*)d_in[0];
  const float* dst_feat = (const float*)d_in[1];
  const int*   dst      = (const int*)d_in[2];
  const float* W_self   = (const float*)d_in[3];
  const float* b_self   = (const float*)d_in[4];
  const float* W_neigh  = (const float*)d_in[5];
  const float* b_neigh  = (const float*)d_in[6];
  float* out = (float*)d_out;
  const int E = in_sizes[2];

  unsigned short* wt   = (unsigned short*)d_ws;           // 64KB repacked weights
  float*          bias = (float*)((char*)d_ws + 65536);   // 512B

  k_prep<<<128, 256, 0, stream>>>(W_self, W_neigh, b_self, b_neigh, wt, bias);

  int nwg = (E + SPAN - 1) / SPAN;
  k_fused<<<nwg, 512, 0, stream>>>(src_feat, dst_feat, dst, wt, bias, out, E, nwg);
}

// Round 13
// 170.070 us; speedup vs baseline: 2.4058x; 2.4058x over previous
//
#include <hip/hip_runtime.h>

typedef float f32x4 __attribute__((ext_vector_type(4)));
typedef __bf16 bf16x8 __attribute__((ext_vector_type(8)));

typedef __attribute__((address_space(3))) unsigned char lds_u8;
typedef __attribute__((address_space(1))) const unsigned char g_u8c;

__device__ __forceinline__ unsigned short f2bf(float f) {
  unsigned int u = __float_as_uint(f);
  u += 0x7FFFu + ((u >> 16) & 1u);   // round-to-nearest-even
  return (unsigned short)(u >> 16);
}
__device__ __forceinline__ bf16x8 cvt8(float4 x, float4 y) {
  bf16x8 r;
  r[0] = (__bf16)x.x; r[1] = (__bf16)x.y; r[2] = (__bf16)x.z; r[3] = (__bf16)x.w;
  r[4] = (__bf16)y.x; r[5] = (__bf16)y.y; r[6] = (__bf16)y.z; r[7] = (__bf16)y.w;
  return r;
}
__device__ __forceinline__ void gload16(const void* g, void* l) {
  __builtin_amdgcn_global_load_lds((g_u8c*)g, (lds_u8*)l, 16, 0, 0);
}

// ---- k_prep: weights -> bf16, fragment-contiguous (validated r7-r12) ----
// b-frag for (kt,ctg): wt[(kt*8+ctg)*512 + lane*8 + j]; kt 0..3 = W_self,
// kt 4..7 = W_neigh; lane=lg*16+l15 -> (n=ctg*16+l15, k=kt*32+lg*8+j).
__global__ void k_prep(const float* __restrict__ Ws, const float* __restrict__ Wn,
                       const float* __restrict__ bs, const float* __restrict__ bn,
                       unsigned short* __restrict__ wt, float* __restrict__ bias) {
  int idx = blockIdx.x * 256 + threadIdx.x;   // 0..32767
  int n = idx >> 8, k = idx & 255;
  float v = (k < 128) ? Ws[k * 128 + n] : Wn[(k - 128) * 128 + n];
  int ct = n >> 4, l15 = n & 15, kt = k >> 5, lg = (k >> 3) & 3, j = k & 7;
  wt[(((kt << 3) | ct) << 9) + (((lg << 4) | l15) << 3) + j] = f2bf(v);
  if (idx < 128) bias[idx] = bs[idx] + bn[idx];
}

#define SPAN 256   // 8 tiles x 32 rows per WG

// ---- Fused: LDS-staged A (1x fetch), persistent B (64 VGPR), MFMA-scan,
// double-buffered counted-vmcnt pipeline; <<4 swizzle = conflict-free. ----
__global__ __launch_bounds__(256) void k_fused(
    const float* __restrict__ src, const float* __restrict__ dstf,
    const int* __restrict__ dst, const unsigned short* __restrict__ wt,
    const float* __restrict__ bias, float* __restrict__ out, int E, int nwg)
{
  __shared__ __align__(16) unsigned char sbuf[2][16384];   // src f32 32x512 swz<<4
  __shared__ __align__(16) unsigned char dbuf[2][16384];   // dstf f32 32x512 swz<<4
  __shared__ __align__(16) unsigned char ylds[4][2560];    // per-wave Y bounce
  __shared__ float cbuf[4][128];                           // per-wave presum
  __shared__ unsigned smask[8];                            // per-tile reset masks
  const int lane = threadIdx.x & 63, wid = threadIdx.x >> 6;
  const int l15 = lane & 15, lg = lane >> 4, l31 = lane & 31;
  const long emax = (long)E - 1;

  // bijective XCD swizzle (m204)
  const int bid = blockIdx.x;
  const int q = nwg >> 3, r = nwg & 7;
  const int xcd = bid & 7, ix = bid >> 3;
  const int swb = (xcd < r ? xcd * (q + 1) : r * (q + 1) + (xcd - r) * q) + ix;

  const long W0 = (long)swb * SPAN;
  if (W0 >= E) return;                          // WG-uniform
  const long Wend = (W0 + SPAN < (long)E) ? W0 + SPAN : (long)E;
  const int nt = (int)((Wend - W0 + 31) >> 5);

  unsigned char* yw = ylds[wid];
  float* cw = cbuf[wid];
  float bc[2] = { bias[wid * 32 + l15], bias[wid * 32 + 16 + l15] };

  // ---- reset masks for all 8 tiles (one ballot per wave; rows = threadIdx) ----
  {
    long rc = W0 + threadIdx.x; if (rc > emax) rc = emax;
    long rp = rc - 1; if (rp < 0) rp = 0;
    int dc = dst[rc], dp = dst[rp];
    unsigned long long bal = __ballot((W0 + threadIdx.x > 0) && (dc != dp));
    if (lane == 0) {
      smask[wid * 2]     = (unsigned)(bal & 0xFFFFFFFFull);
      smask[wid * 2 + 1] = (unsigned)(bal >> 32);
    }
  }

  // ---- persistent B: cols [wid*32, wid*32+32), 16 frags = 64 VGPRs ----
  bf16x8 B[8][2];
  #pragma unroll
  for (int kt = 0; kt < 8; ++kt)
    #pragma unroll
    for (int ctt = 0; ctt < 2; ++ctt)
      B[kt][ctt] = *(const bf16x8*)(wt + (((kt << 3) | (wid * 2 + ctt)) << 9) + (lane << 3));

  // ---- stage tile 0 into slot 0 (linear LDS dest, inverse-swz source) ----
  #pragma unroll
  for (int qd = 0; qd < 4; ++qd) {
    int i = wid * 4 + qd;
    int r2 = i * 2 + (lane >> 5);
    long gr = W0 + r2; if (gr > emax) gr = emax;
    int colb = (l31 << 4) ^ ((r2 & 7) << 4);
    gload16((const char*)src + gr * 512 + colb, sbuf[0] + i * 1024);
    gload16((const char*)dstf + gr * 512 + colb, dbuf[0] + i * 1024);
  }

  // ---- prologue: bucket start before W0 -> pos0, carry[2] (output space) ----
  int d0 = dst[W0];
  long back = W0 - 1 - lane;
  long backc = back < 0 ? 0 : back;
  int bd = dst[backc];
  unsigned long long mm = __ballot((back >= 0) && (bd == d0));
  unsigned long long nmm = ~mm;
  int L = (nmm == 0ull) ? 64 : __builtin_ctzll(nmm);
  long s = W0 - L;
  while (s > 0 && dst[s - 1] == d0) --s;        // bucket >64 deep: ~never
  int pos0 = (int)(W0 - s);

  float carry[2] = {0.f, 0.f};
  if (pos0 > 0) {
    float px = 0.f, py = 0.f;                   // presum of src rows [s,W0)
    for (long e = s; e < W0; ) {
      int nb = (int)(W0 - e); if (nb > 8) nb = 8;
      float2 tv[8];
      #pragma unroll
      for (int j = 0; j < 8; ++j)
        if (j < nb) tv[j] = *(const float2*)(src + (e + j) * 128 + lane * 2);
      #pragma unroll
      for (int j = 0; j < 8; ++j)
        if (j < nb) { px += tv[j].x; py += tv[j].y; }
      e += nb;
    }
    cw[lane * 2] = px; cw[lane * 2 + 1] = py;
    asm volatile("s_waitcnt lgkmcnt(0)" ::: "memory");
    #pragma unroll
    for (int ctt = 0; ctt < 2; ++ctt) {
      f32x4 accc = {0.f, 0.f, 0.f, 0.f};        // carry = presum @ Wn (row-0 MFMA)
      #pragma unroll
      for (int kt = 0; kt < 4; ++kt) {
        float4 x = {0,0,0,0}, y = {0,0,0,0};
        if (l15 == 0) {
          x = *(const float4*)(cw + kt * 32 + lg * 8);
          y = *(const float4*)(cw + kt * 32 + lg * 8 + 4);
        }
        bf16x8 a = cvt8(x, y);
        accc = __builtin_amdgcn_mfma_f32_16x16x32_bf16(a, B[kt + 4][ctt], accc, 0, 0, 0);
      }
      carry[ctt] = __shfl(accc[0], l15);        // D row0: lanes 0..15, comp 0
    }
  }

  __syncthreads();   // tile 0 staged (vmcnt0+lgkm0), masks visible

  // ---- main loop: VMEM per iter = [8 stage][16 stores] exactly ----
  for (int t = 0; t < nt; ++t) {
    const long tb = W0 + (long)t * 32;
    const unsigned char* sb = sbuf[t & 1];
    const unsigned char* db = dbuf[t & 1];
    const unsigned mask = smask[t];

    // prefetch next tile (flies under compute + stores, counted at loop end)
    if (t + 1 < nt) {
      #pragma unroll
      for (int qd = 0; qd < 4; ++qd) {
        int i = wid * 4 + qd;
        int r2 = i * 2 + (lane >> 5);
        long gr = tb + 32 + r2; if (gr > emax) gr = emax;
        int colb = (l31 << 4) ^ ((r2 & 7) << 4);
        gload16((const char*)src + gr * 512 + colb, sbuf[(t + 1) & 1] + i * 1024);
        gload16((const char*)dstf + gr * 512 + colb, dbuf[(t + 1) & 1] + i * 1024);
      }
      asm volatile("" ::: "memory");            // pin stage group position
    }

    // ---- O = dstf@Ws, Y = src@Wn from LDS (swz<<4: uniform 8-slot spread) ----
    f32x4 accO[2][2] = {{{0,0,0,0},{0,0,0,0}},{{0,0,0,0},{0,0,0,0}}};
    f32x4 accY[2][2] = {{{0,0,0,0},{0,0,0,0}},{{0,0,0,0},{0,0,0,0}}};
    #pragma unroll
    for (int rt = 0; rt < 2; ++rt) {
      int row = rt * 16 + l15;
      const int sw = (row & 7) << 4;
      #pragma unroll
      for (int kt = 0; kt < 4; ++kt) {
        int c0 = kt * 128 + lg * 32;
        float4 sx = *(const float4*)(sb + row * 512 + (c0 ^ sw));
        float4 sy = *(const float4*)(sb + row * 512 + ((c0 + 16) ^ sw));
        float4 dx = *(const float4*)(db + row * 512 + (c0 ^ sw));
        float4 dy = *(const float4*)(db + row * 512 + ((c0 + 16) ^ sw));
        bf16x8 aS = cvt8(sx, sy);
        bf16x8 aD = cvt8(dx, dy);
        #pragma unroll
        for (int ctt = 0; ctt < 2; ++ctt) {
          accO[rt][ctt] = __builtin_amdgcn_mfma_f32_16x16x32_bf16(aD, B[kt][ctt], accO[rt][ctt], 0, 0, 0);
          accY[rt][ctt] = __builtin_amdgcn_mfma_f32_16x16x32_bf16(aS, B[kt + 4][ctt], accY[rt][ctt], 0, 0, 0);
        }
      }
    }

    // ---- M fragments: M[r][e] = 1 iff start(r) <= e <= r ----
    bf16x8 Mf[2];
    #pragma unroll
    for (int rt = 0; rt < 2; ++rt) {
      int rr = rt * 16 + l15;
      unsigned bits = mask & (0xFFFFFFFFu >> (31 - rr));
      int sr = (bits == 0) ? 0 : (31 - __clz(bits));
      union { unsigned u[4]; bf16x8 v; } mu;
      #pragma unroll
      for (int p = 0; p < 4; ++p) {
        int e0 = lg * 8 + p * 2;
        unsigned lo = (e0 >= sr && e0 <= rr) ? 0x3F80u : 0u;
        unsigned hi = (e0 + 1 >= sr && e0 + 1 <= rr) ? 0x3F80u : 0u;
        mu.u[p] = lo | (hi << 16);
      }
      Mf[rt] = mu.v;
    }

    // ---- Z = M@Y per ct (wave-private LDS bounce, stride 80) ----
    f32x4 accZ[2][2];
    #pragma unroll
    for (int ctt = 0; ctt < 2; ++ctt) {
      #pragma unroll
      for (int rt = 0; rt < 2; ++rt) {
        unsigned lo = (unsigned)f2bf(accY[rt][ctt][0]) | ((unsigned)f2bf(accY[rt][ctt][1]) << 16);
        unsigned hi = (unsigned)f2bf(accY[rt][ctt][2]) | ((unsigned)f2bf(accY[rt][ctt][3]) << 16);
        *(unsigned long long*)(yw + ctt * 1280 + l15 * 80 + rt * 32 + lg * 8) =
            (unsigned long long)lo | ((unsigned long long)hi << 32);
      }
      asm volatile("s_waitcnt lgkmcnt(0)" ::: "memory");
      bf16x8 yb = *(const bf16x8*)(yw + ctt * 1280 + l15 * 80 + lg * 16);
      #pragma unroll
      for (int rt = 0; rt < 2; ++rt) {
        f32x4 z = {0.f, 0.f, 0.f, 0.f};
        accZ[rt][ctt] = __builtin_amdgcn_mfma_f32_16x16x32_bf16(Mf[rt], yb, z, 0, 0, 0);
      }
    }

    // raw Z[31] for carry update (row 31 -> lane 48+l15, comp 3)
    float z31[2];
    #pragma unroll
    for (int ctt = 0; ctt < 2; ++ctt) z31[ctt] = __shfl(accZ[1][ctt][3], 48 + l15);

    // ---- epilogue: scale by 1/count, +carry on head rows, +O+bias, store ----
    #pragma unroll
    for (int rt = 0; rt < 2; ++rt) {
      #pragma unroll
      for (int i = 0; i < 4; ++i) {
        int rr = rt * 16 + lg * 4 + i;
        unsigned bits = mask & (0xFFFFFFFFu >> (31 - rr));
        float cnt, u;
        if (bits == 0) { cnt = (float)(rr + 1 + pos0); u = 1.f; }
        else { cnt = (float)(rr - (31 - __clz(bits)) + 1); u = 0.f; }
        float inv = __builtin_amdgcn_rcpf(cnt);
        long grow = tb + rr;
        if (grow < E) {
          float* op = out + grow * 128 + wid * 32 + l15;
          op[0]  = accO[rt][0][i] + bc[0] + (accZ[rt][0][i] + u * carry[0]) * inv;
          op[16] = accO[rt][1][i] + bc[1] + (accZ[rt][1][i] + u * carry[1]) * inv;
        }
      }
    }

    // carry/pos0 update (wave-uniform)
    if (mask == 0) { carry[0] += z31[0]; carry[1] += z31[1]; pos0 += 32; }
    else           { carry[0]  = z31[0]; carry[1]  = z31[1]; pos0 = __clz(mask) + 1; }

    if (t + 1 < nt) {
      // counted wait: youngest 16 VMEM = this tile's stores; the 8 stage ops
      // are older -> retired. Stores keep flying across the barrier.
      asm volatile("s_waitcnt vmcnt(16)" ::: "memory");
      __builtin_amdgcn_s_barrier();
    }
  }
}

extern "C" void kernel_launch(void* const* d_in, const int* in_sizes, int n_in,
                              void* d_out, int out_size, void* d_ws, size_t ws_size,
                              hipStream_t stream) {
  const float* src_feat = (const float*)d_in[0];
  const float* dst_feat = (const float*)d_in[1];
  const int*   dst      = (const int*)d_in[2];
  const float* W_self   = (const float*)d_in[3];
  const float* b_self   = (const float*)d_in[4];
  const float* W_neigh  = (const float*)d_in[5];
  const float* b_neigh  = (const float*)d_in[6];
  float* out = (float*)d_out;
  const int E = in_sizes[2];

  unsigned short* wt   = (unsigned short*)d_ws;           // 64KB repacked weights
  float*          bias = (float*)((char*)d_ws + 65536);   // 512B

  k_prep<<<128, 256, 0, stream>>>(W_self, W_neigh, b_self, b_neigh, wt, bias);

  int nwg = (E + SPAN - 1) / SPAN;
  k_fused<<<nwg, 256, 0, stream>>>(src_feat, dst_feat, dst, wt, bias, out, E, nwg);
}